// Round 3
// baseline (993.875 us; speedup 1.0000x reference)
//
#include <hip/hip_runtime.h>
#include <hip/hip_bf16.h>

// BilinearChebConv via Chebyshev-identity restructure:
//   T2 = 2L^2 - I, T3 = 2L*T2 - L, T4 = 2*T2^2 - I   (all symmetric)
//   Y_j = T_j(Lr) @ X   (G1: M=6144, B^T = X^T)
//   Z_{i,j} = Y_i @ T_j(Lc)  (G2: M=7680, N=6144)
//   out[o] = sum_ij theta[i,j,o] * Z_{i,j} + bias[o]
// R4: G1/G2 on 256x256 8-phase pipelined kernel (T2 swizzle + T3/T4 counted
// vmcnt + T5 setprio). 128x128 2-phase kernel kept for S1/S2 (small grids).
// R5: combine theta/bias in LDS. R5 regressed combine (z[25][4] f32 = 130+
// VGPR -> 2 waves/SIMD).
// R6: combine holds Z PACKED (uint2 zr[25], 50 VGPR), unpacks per use;
// bounds (256,4) -> 4 waves/SIMD. XCD-aware bijective block swizzle (T1) in
// both GEMMs. Lr/Lc casts fused into one dispatch.

#define NDIM 1536
#define PM (NDIM * NDIM)  // 2359296
#define NK 24             // K-tiles of 64 over K=1536

typedef __attribute__((ext_vector_type(8))) short bf16x8;
typedef __attribute__((ext_vector_type(4))) float f32x4;

__device__ inline void gload_lds16(const void* g, void* l) {
  __builtin_amdgcn_global_load_lds(
      (const __attribute__((address_space(1))) void*)g,
      (__attribute__((address_space(3))) void*)l, 16, 0, 0);
}

__device__ inline unsigned short f2bf(float f) {
  __hip_bfloat16 h = __float2bfloat16(f);
  return *reinterpret_cast<unsigned short*>(&h);
}
__device__ inline float bf2f(unsigned short u) {
  return __uint_as_float((unsigned)u << 16);
}

struct ZSet {
  const unsigned short* A;   // M x 1536 row-major bf16
  const unsigned short* Bt;  // B^T rows (B symmetric => B rows), multi-plane via jn
  unsigned short* out;       // multi-plane via jn (stride 5*PM per j-plane-group)
  const unsigned short* Cp;  // mode 1 subtrahend
  int mode;                  // 0: A@B ; 1: 2*A@B - Cp ; 2: 2*A@B - I
};
struct ZSet4 { ZSet z[4]; };

// XCD-aware bijective swizzle over the (x,y) grid. Requires nwg%8==0 (all
// our grids are). Each XCD gets a contiguous by-major chunk -> A-panel reuse
// lands in its private L2.
__device__ inline void xcd_swizzle(int& bx, int& by) {
  const int gx = gridDim.x;
  const int nwg = gx * gridDim.y;
  int lin = by * gx + bx;
  const int nper = nwg >> 3;
  lin = (lin & 7) * nper + (lin >> 3);
  bx = lin % gx;
  by = lin / gx;
}

// Phase glue: raw barrier (NO full vmcnt drain), explicit lgkm drain of this
// phase's ds_reads, sched_barrier per rule #18, setprio around MFMA cluster.
#define PH_MID()                                       \
  do {                                                 \
    asm volatile("" ::: "memory");                     \
    __builtin_amdgcn_s_barrier();                      \
    asm volatile("s_waitcnt lgkmcnt(0)" ::: "memory"); \
    __builtin_amdgcn_sched_barrier(0);                 \
    __builtin_amdgcn_s_setprio(1);                     \
  } while (0)

#define PH_END()                                       \
  do {                                                 \
    __builtin_amdgcn_s_setprio(0);                     \
    asm volatile("" ::: "memory");                     \
    __builtin_amdgcn_s_barrier();                      \
  } while (0)

// 256x256 tile, BK=64, 8 waves (2M x 4N), 4 phases per K-tile, double-buffered
// 128 KiB LDS. Per phase: {ds_read subtile | stage 1 half-tile | barrier |
// lgkmcnt(0) | 16 MFMA | barrier}. vmcnt(6) once per K-tile (phase 4) keeps
// 3 half-tiles (kt+2) in flight across barriers.
// LDS layout: As[buf][h][wm(2)][64][64], Bs[buf][h][wn(4)][32][64]; 16-B slot
// XOR-swizzle (slot ^ (row&7)) applied on the GLOBAL source during staging
// (linear LDS dest, per guide m173/m201) and on the ds_read address.
__global__ __launch_bounds__(512, 2) void gemm256_k(ZSet4 zs) {
  const ZSet zp = zs.z[blockIdx.z];
  __shared__ __align__(16) unsigned short As[2][2][8192];  // 64 KiB
  __shared__ __align__(16) unsigned short Bs[2][2][8192];  // 64 KiB
  int bswx = blockIdx.x, bswy = blockIdx.y;
  xcd_swizzle(bswx, bswy);
  const int tid = threadIdx.x;
  const int lane = tid & 63;
  const int wave = tid >> 6;
  const int wm = wave >> 2, wn = wave & 3;
  const int gm0 = bswy * 256;
  const int jn = bswx / 6;             // which B/out plane along N
  const int nloc0 = (bswx % 6) * 256;  // col within plane
  const int q = lane >> 4;
  const int rowl = lane & 15;
  const unsigned short* Ab = zp.A;
  const unsigned short* Btb = zp.Bt + (size_t)jn * PM;
  unsigned short* outb = zp.out + (size_t)jn * 5 * PM;

  bf16x8 a[4][2];            // current A half-frags [mt][ks]
  bf16x8 b0[2][2], b1[2][2]; // B half0 / half1 frags [nt][ks]
  f32x4 acc00[4][2] = {}, acc01[4][2] = {}, acc10[4][2] = {}, acc11[4][2] = {};

  // Stage one 16 KiB half-tile: 512 threads x 2 x 16 B. LDS dest is
  // wave-uniform base + lane*16 (linear); swizzle folded into global src.
  auto stageA = [&](int buf, int h, int kt) {
#pragma unroll
    for (int l = 0; l < 2; ++l) {
      const int o = (wave * 2 + l) * 1024 + lane * 16;  // byte off in slab
      const int wms = o >> 13;
      const int r = (o >> 7) & 63;
      const int s = (o >> 4) & 7;
      const unsigned short* src =
          Ab + (size_t)(gm0 + wms * 128 + h * 64 + r) * NDIM + kt * 64 +
          ((s ^ (r & 7)) << 3);
      gload_lds16(src, &As[buf][h][(wave * 2 + l) * 512]);
    }
  };
  auto stageB = [&](int buf, int h, int kt) {
#pragma unroll
    for (int l = 0; l < 2; ++l) {
      const int o = (wave * 2 + l) * 1024 + lane * 16;
      const int wns = o >> 12;
      const int r = (o >> 7) & 31;
      const int s = (o >> 4) & 7;
      const unsigned short* src =
          Btb + (size_t)(nloc0 + wns * 64 + h * 32 + r) * NDIM + kt * 64 +
          ((s ^ (r & 7)) << 3);
      gload_lds16(src, &Bs[buf][h][(wave * 2 + l) * 512]);
    }
  };
  auto loadA = [&](int buf, int h) {
#pragma unroll
    for (int mt = 0; mt < 4; ++mt) {
      const int lr = mt * 16 + rowl;
#pragma unroll
      for (int ks = 0; ks < 2; ++ks) {
        const int s0 = ks * 4 + q;
        a[mt][ks] = *(const bf16x8*)&As[buf][h][wm * 4096 + lr * 64 +
                                                ((s0 ^ (lr & 7)) << 3)];
      }
    }
  };
  auto loadB = [&](bf16x8 (&bb)[2][2], int buf, int h) {
#pragma unroll
    for (int nt = 0; nt < 2; ++nt) {
      const int lr = nt * 16 + rowl;
#pragma unroll
      for (int ks = 0; ks < 2; ++ks) {
        const int s0 = ks * 4 + q;
        bb[nt][ks] = *(const bf16x8*)&Bs[buf][h][wn * 2048 + lr * 64 +
                                                 ((s0 ^ (lr & 7)) << 3)];
      }
    }
  };
  auto mfma16 = [&](f32x4 (&ac)[4][2], bf16x8 (&bb)[2][2]) {
#pragma unroll
    for (int mt = 0; mt < 4; ++mt)
#pragma unroll
      for (int nt = 0; nt < 2; ++nt)
#pragma unroll
        for (int ks = 0; ks < 2; ++ks)
          ac[mt][nt] = __builtin_amdgcn_mfma_f32_16x16x32_bf16(
              a[mt][ks], bb[nt][ks], ac[mt][nt], 0, 0, 0);
  };

  // Prologue: kt0 fully (4 half-tiles) + kt1 {A0,B0,B1}; A1 of kt+1 is always
  // staged in ph1 of kt. vmcnt(6) -> kt0's 8 loads done, kt1's 6 in flight.
  stageA(0, 0, 0); stageB(0, 0, 0); stageB(0, 1, 0); stageA(0, 1, 0);
  stageA(1, 0, 1); stageB(1, 0, 1); stageB(1, 1, 1);
  asm volatile("s_waitcnt vmcnt(6)" ::: "memory");
  __builtin_amdgcn_s_barrier();

  // Region-freedom schedule (stage target last read >=1 barrier earlier):
  //  ph1 reads A[b][0],B[b][0]; stages (kt+1).A1 -> As[b^1][1] (read kt-1 ph3)
  //  ph2 reads B[b][1];          stages (kt+2).A0 -> As[b][0]  (read ph1)
  //  ph3 reads A[b][1];          stages (kt+2).B0 -> Bs[b][0]  (read ph1)
  //  ph4 (regs only);            stages (kt+2).B1 -> Bs[b][1]  (read ph2)
  auto ktile = [&](int kt, int b) {
    // phase 1: quadrant (m-half0, n-half0)
    loadA(b, 0);
    loadB(b0, b, 0);
    if (kt + 1 < NK) stageA(b ^ 1, 1, kt + 1);
    PH_MID();
    mfma16(acc00, b0);
    PH_END();
    // phase 2: (m-half0, n-half1)
    loadB(b1, b, 1);
    if (kt + 2 < NK) stageA(b, 0, kt + 2);
    PH_MID();
    mfma16(acc01, b1);
    PH_END();
    // phase 3: (m-half1, n-half1)
    loadA(b, 1);
    if (kt + 2 < NK) stageB(b, 0, kt + 2);
    PH_MID();
    mfma16(acc11, b1);
    PH_END();
    // phase 4: (m-half1, n-half0) — no ds_reads; counted vmcnt once per K-tile
    if (kt + 2 < NK) {
      stageB(b, 1, kt + 2);
      asm volatile("s_waitcnt vmcnt(6)" ::: "memory");
    } else {
      asm volatile("s_waitcnt vmcnt(0)" ::: "memory");
    }
    PH_MID();
    mfma16(acc10, b0);
    PH_END();
  };
  for (int kt = 0; kt < NK; kt += 2) {
    ktile(kt, 0);
    ktile(kt + 1, 1);
  }

  // Epilogue. C/D layout: col = lane&15, row = (lane>>4)*4 + reg.
  auto writeQ = [&](f32x4 (&ac)[4][2], int mh, int nh) {
#pragma unroll
    for (int mt = 0; mt < 4; ++mt)
#pragma unroll
      for (int nt = 0; nt < 2; ++nt)
#pragma unroll
        for (int v = 0; v < 4; ++v) {
          const int row = gm0 + wm * 128 + mh * 64 + mt * 16 + q * 4 + v;
          const int col = nloc0 + wn * 64 + nh * 32 + nt * 16 + rowl;
          const size_t idx = (size_t)row * NDIM + col;
          float val = ac[mt][nt][v];
          if (zp.mode == 1) val = 2.0f * val - bf2f(zp.Cp[idx]);
          if (zp.mode == 2) val = 2.0f * val - (row == col ? 1.0f : 0.0f);
          outb[idx] = f2bf(val);
        }
  };
  writeQ(acc00, 0, 0);
  writeQ(acc01, 0, 1);
  writeQ(acc11, 1, 1);
  writeQ(acc10, 1, 0);
}

// 128x128 tile, 4 waves (2x2), 16x16x32 bf16 MFMA, global_load_lds width-16.
// Kept for S1/S2 (small grids: 288/576 blocks at 128^2 vs 72/144 at 256^2).
__global__ __launch_bounds__(256) void gemm_k(ZSet4 zs) {
  const ZSet zp = zs.z[blockIdx.z];
  __shared__ __align__(16) unsigned short As[128 * 32];
  __shared__ __align__(16) unsigned short Bs[128 * 32];
  int bswx = blockIdx.x, bswy = blockIdx.y;
  xcd_swizzle(bswx, bswy);
  const int tid = threadIdx.x;
  const int lane = tid & 63;
  const int wave = tid >> 6;
  const int wm = wave >> 1, wn = wave & 1;
  const int gm0 = bswy * 128;
  const int jn = bswx / 12;             // which B/out plane along N
  const int nloc0 = (bswx % 12) * 128;  // col within plane
  const int q = lane >> 4;
  const int rowl = lane & 15;

  const unsigned short* Btb = zp.Bt + (size_t)jn * PM;
  unsigned short* outb = zp.out + (size_t)jn * 5 * PM;

  f32x4 acc[4][4] = {};

  for (int k0 = 0; k0 < NDIM; k0 += 32) {
#pragma unroll
    for (int l = 0; l < 2; ++l) {
      int f = l * 256 + wave * 64 + lane;  // 512 16B chunks per 128x32 tile
      int r = f >> 2, kc = f & 3;
      const unsigned short* ga = zp.A + (size_t)(gm0 + r) * NDIM + k0 + kc * 8;
      const unsigned short* gb = Btb + (size_t)(nloc0 + r) * NDIM + k0 + kc * 8;
      unsigned short* la = &As[(size_t)(l * 256 + wave * 64) * 8];
      unsigned short* lb = &Bs[(size_t)(l * 256 + wave * 64) * 8];
      gload_lds16(ga, la);
      gload_lds16(gb, lb);
    }
    __syncthreads();
    bf16x8 af[4], bfv[4];
#pragma unroll
    for (int t = 0; t < 4; ++t) {
      af[t] = *(const bf16x8*)&As[(wm * 64 + t * 16 + rowl) * 32 + q * 8];
      bfv[t] = *(const bf16x8*)&Bs[(wn * 64 + t * 16 + rowl) * 32 + q * 8];
    }
#pragma unroll
    for (int mt = 0; mt < 4; ++mt)
#pragma unroll
      for (int nt = 0; nt < 4; ++nt)
        acc[mt][nt] = __builtin_amdgcn_mfma_f32_16x16x32_bf16(
            af[mt], bfv[nt], acc[mt][nt], 0, 0, 0);
    __syncthreads();
  }

  // C/D layout: col = lane&15, row = (lane>>4)*4 + reg
#pragma unroll
  for (int mt = 0; mt < 4; ++mt) {
#pragma unroll
    for (int nt = 0; nt < 4; ++nt) {
#pragma unroll
      for (int v = 0; v < 4; ++v) {
        int row = gm0 + wm * 64 + mt * 16 + q * 4 + v;
        int col = nloc0 + wn * 64 + nt * 16 + rowl;
        size_t idx = (size_t)row * NDIM + col;
        float val = acc[mt][nt][v];
        if (zp.mode == 1) val = 2.0f * val - bf2f(zp.Cp[idx]);
        if (zp.mode == 2) val = 2.0f * val - (row == col ? 1.0f : 0.0f);
        outb[idx] = f2bf(val);
      }
    }
  }
}

// X^T (bf16, transposed) AND straight bf16 cast of X in one pass.
__global__ void transpose_f2b(const float* __restrict__ in,
                              unsigned short* __restrict__ out16,
                              unsigned short* __restrict__ outS) {
  __shared__ float tile[32][33];
  int bx = blockIdx.x, by = blockIdx.y;
  int tx = threadIdx.x;
#pragma unroll
  for (int r = threadIdx.y; r < 32; r += 8) {
    float v = in[(size_t)(by * 32 + r) * NDIM + bx * 32 + tx];
    tile[r][tx] = v;
    outS[(size_t)(by * 32 + r) * NDIM + bx * 32 + tx] = f2bf(v);
  }
  __syncthreads();
  int ox = by * 32 + tx;
#pragma unroll
  for (int r = threadIdx.y; r < 32; r += 8)
    out16[(size_t)(bx * 32 + r) * NDIM + ox] = f2bf(tile[tx][r]);
}

// Two-plane bf16 cast (Lr and Lc in one dispatch via blockIdx.y).
__global__ void cast2_bf16_k(const float* __restrict__ inA,
                             unsigned short* __restrict__ outA,
                             const float* __restrict__ inB,
                             unsigned short* __restrict__ outB) {
  const float* in = blockIdx.y ? inB : inA;
  unsigned short* out = blockIdx.y ? outB : outA;
  int i = (blockIdx.x * 256 + threadIdx.x) * 4;
  float4 v = *(const float4*)(in + i);
  ushort4 r;
  r.x = f2bf(v.x); r.y = f2bf(v.y); r.z = f2bf(v.z); r.w = f2bf(v.w);
  *(ushort4*)(out + i) = r;
}

// Z: 25 bf16 planes, plane c = j*5+i. theta flat: i*160 + j*32 + o.
// R6: 4 px/thread, Z kept PACKED in uint2 zr[25] (50 VGPR), unpacked per use
// (1 shift/and + FMA per element — VALU ~45 us, hidden under the 67-us memory
// floor). bounds (256,4) caps VGPR at 128 -> 4 waves/SIMD. Accumulation order
// over c identical to all previous versions (c ascending, f32 FMA).
__global__ __launch_bounds__(256, 4) void combine_k(
    const unsigned short* __restrict__ Z,
    const float* __restrict__ theta,
    const float* __restrict__ bias,
    float* __restrict__ out) {
  __shared__ float th[800];
  __shared__ float bs[32];
  const int tid = threadIdx.x;
  for (int t = tid; t < 800; t += 256) th[t] = theta[t];
  if (tid < 32) bs[tid] = bias[tid];
  __syncthreads();

  const size_t p0 = (size_t)(blockIdx.x * 256 + tid) * 4;
  uint2 zr[25];
#pragma unroll
  for (int c = 0; c < 25; ++c)
    zr[c] = *(const uint2*)(Z + (size_t)c * PM + p0);

#pragma unroll 4
  for (int o = 0; o < 32; ++o) {
    float b = bs[o];
    float a0 = b, a1 = b, a2 = b, a3 = b;
#pragma unroll
    for (int c = 0; c < 25; ++c) {
      const int i = c % 5, j = c / 5;       // compile-time after unroll
      float t = th[i * 160 + j * 32 + o];   // uniform addr -> broadcast
      a0 += t * __uint_as_float(zr[c].x << 16);
      a1 += t * __uint_as_float(zr[c].x & 0xffff0000u);
      a2 += t * __uint_as_float(zr[c].y << 16);
      a3 += t * __uint_as_float(zr[c].y & 0xffff0000u);
    }
    float4 w; w.x = a0; w.y = a1; w.z = a2; w.w = a3;
    *(float4*)(out + (size_t)o * PM + p0) = w;
  }
}

extern "C" void kernel_launch(void* const* d_in, const int* in_sizes, int n_in,
                              void* d_out, int out_size, void* d_ws, size_t ws_size,
                              hipStream_t stream) {
  (void)in_sizes; (void)n_in; (void)out_size; (void)ws_size;
  const float* X = (const float*)d_in[0];
  const float* Lr = (const float*)d_in[1];
  const float* Lc = (const float*)d_in[2];
  const float* theta = (const float*)d_in[3];
  const float* bias = (const float*)d_in[4];
  float* out = (float*)d_out;

  // Workspace: Zall(25) + Tr(4) + Tc(4) + Xt(1) = 34 bf16 planes = 160 MiB
  unsigned short* Zall = (unsigned short*)d_ws;      // plane c = j*5 + i
  unsigned short* Tr = Zall + (size_t)25 * PM;       // [Lr, T2r, T3r, T4r]
  unsigned short* Tc = Tr + (size_t)4 * PM;          // [Lc, T2c, T3c, T4c]
  unsigned short* Xt = Tc + (size_t)4 * PM;

  unsigned short* Tr0 = Tr;                 unsigned short* Tc0 = Tc;
  unsigned short* Tr1 = Tr + (size_t)PM;    unsigned short* Tc1 = Tc + (size_t)PM;
  unsigned short* Tr2 = Tr + (size_t)2*PM;  unsigned short* Tc2 = Tc + (size_t)2*PM;
  unsigned short* Tr3 = Tr + (size_t)3*PM;  unsigned short* Tc3 = Tc + (size_t)3*PM;

  cast2_bf16_k<<<dim3(PM / 1024, 2), 256, 0, stream>>>(Lr, Tr0, Lc, Tc0);
  // X: transposed bf16 (Xt) + straight bf16 (Zall plane 0) in one pass
  transpose_f2b<<<dim3(48, 48), dim3(32, 8), 0, stream>>>(X, Xt, Zall);

  // S1: T2r = 2*Lr@Lr - I ; T2c = 2*Lc@Lc - I      (z-batched, 128^2 kernel)
  {
    ZSet4 a{};
    a.z[0] = {Tr0, Tr0, Tr1, nullptr, 2};
    a.z[1] = {Tc0, Tc0, Tc1, nullptr, 2};
    gemm_k<<<dim3(12, 12, 2), 256, 0, stream>>>(a);
  }
  // S2: T3 = 2*L@T2 - L ; T4 = 2*T2@T2 - I   (both axes, z-batched)
  {
    ZSet4 a{};
    a.z[0] = {Tr0, Tr1, Tr2, Tr0, 1};
    a.z[1] = {Tr1, Tr1, Tr3, nullptr, 2};
    a.z[2] = {Tc0, Tc1, Tc2, Tc0, 1};
    a.z[3] = {Tc1, Tc1, Tc3, nullptr, 2};
    gemm_k<<<dim3(12, 12, 4), 256, 0, stream>>>(a);
  }
  // G1: Y_j = T_j(Lr) @ X, j=1..4  -> Zall planes 1..4.  A = Tr stacked
  // (M=6144), B^T = Xt, N=1536 (jn==0). 256^2 8-phase kernel.
  {
    ZSet4 a{};
    a.z[0] = {Tr, Xt, Zall + (size_t)PM, nullptr, 0};
    gemm256_k<<<dim3(6, 24, 1), 512, 0, stream>>>(a);
  }
  // G2: Z_{i,j} = Y_i @ T_j(Lc). A = Zall[0..4] (M=7680), B planes via jn,
  // out plane group stride 5*PM -> Zall plane (1+jn)*5 + i. 256^2 kernel.
  {
    ZSet4 a{};
    a.z[0] = {Zall, Tc0, Zall + (size_t)5 * PM, nullptr, 0};
    gemm256_k<<<dim3(24, 30, 1), 512, 0, stream>>>(a);
  }

  combine_k<<<PM / 1024, 256, 0, stream>>>(Zall, theta, bias, out);
}

// Round 4
// 659.159 us; speedup vs baseline: 1.5078x; 1.5078x over previous
//
#include <hip/hip_runtime.h>
#include <hip/hip_bf16.h>

// BilinearChebConv via Chebyshev-identity restructure:
//   T2 = 2L^2 - I, T3 = 2L*T2 - L, T4 = 2*T2^2 - I   (all symmetric)
//   Y_j = T_j(Lr) @ X   (G1: M=6144, B^T = X^T)
//   Z_{i,j} = Y_i @ T_j(Lc)  (G2: M=7680, N=6144)
//   out[o] = sum_ij theta[i,j,o] * Z_{i,j} + bias[o]
// R4: G1/G2 on 256x256 8-phase pipelined kernel (T2 swizzle + T3/T4 counted
// vmcnt + T5 setprio). 128x128 2-phase kernel kept for S1/S2.
// R6 (prev round): XCD swizzle + (256,4)-clamped combine — BOTH regressed:
//   - clamp forced 64 VGPR < 50-reg zr[] live set -> scratch spill (FETCH
//     681 MB, WRITE 752 MB, 435 us).
//   - XCD swizzle de-synchronized the B-window across XCDs in an L3-resident
//     working set (+45 us across GEMMs).
// R7 (this): revert swizzle; combine = packed zr[25] + plain bounds(256)
// (no clamp -> no spill), theta/bias in LDS, nontemporal out stores.

#define NDIM 1536
#define PM (NDIM * NDIM)  // 2359296
#define NK 24             // K-tiles of 64 over K=1536

typedef __attribute__((ext_vector_type(8))) short bf16x8;
typedef __attribute__((ext_vector_type(4))) float f32x4;

__device__ inline void gload_lds16(const void* g, void* l) {
  __builtin_amdgcn_global_load_lds(
      (const __attribute__((address_space(1))) void*)g,
      (__attribute__((address_space(3))) void*)l, 16, 0, 0);
}

__device__ inline unsigned short f2bf(float f) {
  __hip_bfloat16 h = __float2bfloat16(f);
  return *reinterpret_cast<unsigned short*>(&h);
}
__device__ inline float bf2f(unsigned short u) {
  return __uint_as_float((unsigned)u << 16);
}

struct ZSet {
  const unsigned short* A;   // M x 1536 row-major bf16
  const unsigned short* Bt;  // B^T rows (B symmetric => B rows), multi-plane via jn
  unsigned short* out;       // multi-plane via jn (stride 5*PM per j-plane-group)
  const unsigned short* Cp;  // mode 1 subtrahend
  int mode;                  // 0: A@B ; 1: 2*A@B - Cp ; 2: 2*A@B - I
};
struct ZSet4 { ZSet z[4]; };

// Phase glue: raw barrier (NO full vmcnt drain), explicit lgkm drain of this
// phase's ds_reads, sched_barrier per rule #18, setprio around MFMA cluster.
#define PH_MID()                                       \
  do {                                                 \
    asm volatile("" ::: "memory");                     \
    __builtin_amdgcn_s_barrier();                      \
    asm volatile("s_waitcnt lgkmcnt(0)" ::: "memory"); \
    __builtin_amdgcn_sched_barrier(0);                 \
    __builtin_amdgcn_s_setprio(1);                     \
  } while (0)

#define PH_END()                                       \
  do {                                                 \
    __builtin_amdgcn_s_setprio(0);                     \
    asm volatile("" ::: "memory");                     \
    __builtin_amdgcn_s_barrier();                      \
  } while (0)

// 256x256 tile, BK=64, 8 waves (2M x 4N), 4 phases per K-tile, double-buffered
// 128 KiB LDS. Per phase: {ds_read subtile | stage 1 half-tile | barrier |
// lgkmcnt(0) | 16 MFMA | barrier}. vmcnt(6) once per K-tile (phase 4) keeps
// 3 half-tiles (kt+2) in flight across barriers.
// LDS layout: As[buf][h][wm(2)][64][64], Bs[buf][h][wn(4)][32][64]; 16-B slot
// XOR-swizzle (slot ^ (row&7)) applied on the GLOBAL source during staging
// (linear LDS dest, per guide m173/m201) and on the ds_read address.
__global__ __launch_bounds__(512, 2) void gemm256_k(ZSet4 zs) {
  const ZSet zp = zs.z[blockIdx.z];
  __shared__ __align__(16) unsigned short As[2][2][8192];  // 64 KiB
  __shared__ __align__(16) unsigned short Bs[2][2][8192];  // 64 KiB
  const int tid = threadIdx.x;
  const int lane = tid & 63;
  const int wave = tid >> 6;
  const int wm = wave >> 2, wn = wave & 3;
  const int gm0 = blockIdx.y * 256;
  const int jn = blockIdx.x / 6;             // which B/out plane along N
  const int nloc0 = (blockIdx.x % 6) * 256;  // col within plane
  const int q = lane >> 4;
  const int rowl = lane & 15;
  const unsigned short* Ab = zp.A;
  const unsigned short* Btb = zp.Bt + (size_t)jn * PM;
  unsigned short* outb = zp.out + (size_t)jn * 5 * PM;

  bf16x8 a[4][2];            // current A half-frags [mt][ks]
  bf16x8 b0[2][2], b1[2][2]; // B half0 / half1 frags [nt][ks]
  f32x4 acc00[4][2] = {}, acc01[4][2] = {}, acc10[4][2] = {}, acc11[4][2] = {};

  // Stage one 16 KiB half-tile: 512 threads x 2 x 16 B. LDS dest is
  // wave-uniform base + lane*16 (linear); swizzle folded into global src.
  auto stageA = [&](int buf, int h, int kt) {
#pragma unroll
    for (int l = 0; l < 2; ++l) {
      const int o = (wave * 2 + l) * 1024 + lane * 16;  // byte off in slab
      const int wms = o >> 13;
      const int r = (o >> 7) & 63;
      const int s = (o >> 4) & 7;
      const unsigned short* src =
          Ab + (size_t)(gm0 + wms * 128 + h * 64 + r) * NDIM + kt * 64 +
          ((s ^ (r & 7)) << 3);
      gload_lds16(src, &As[buf][h][(wave * 2 + l) * 512]);
    }
  };
  auto stageB = [&](int buf, int h, int kt) {
#pragma unroll
    for (int l = 0; l < 2; ++l) {
      const int o = (wave * 2 + l) * 1024 + lane * 16;
      const int wns = o >> 12;
      const int r = (o >> 7) & 31;
      const int s = (o >> 4) & 7;
      const unsigned short* src =
          Btb + (size_t)(nloc0 + wns * 64 + h * 32 + r) * NDIM + kt * 64 +
          ((s ^ (r & 7)) << 3);
      gload_lds16(src, &Bs[buf][h][(wave * 2 + l) * 512]);
    }
  };
  auto loadA = [&](int buf, int h) {
#pragma unroll
    for (int mt = 0; mt < 4; ++mt) {
      const int lr = mt * 16 + rowl;
#pragma unroll
      for (int ks = 0; ks < 2; ++ks) {
        const int s0 = ks * 4 + q;
        a[mt][ks] = *(const bf16x8*)&As[buf][h][wm * 4096 + lr * 64 +
                                                ((s0 ^ (lr & 7)) << 3)];
      }
    }
  };
  auto loadB = [&](bf16x8 (&bb)[2][2], int buf, int h) {
#pragma unroll
    for (int nt = 0; nt < 2; ++nt) {
      const int lr = nt * 16 + rowl;
#pragma unroll
      for (int ks = 0; ks < 2; ++ks) {
        const int s0 = ks * 4 + q;
        bb[nt][ks] = *(const bf16x8*)&Bs[buf][h][wn * 2048 + lr * 64 +
                                                 ((s0 ^ (lr & 7)) << 3)];
      }
    }
  };
  auto mfma16 = [&](f32x4 (&ac)[4][2], bf16x8 (&bb)[2][2]) {
#pragma unroll
    for (int mt = 0; mt < 4; ++mt)
#pragma unroll
      for (int nt = 0; nt < 2; ++nt)
#pragma unroll
        for (int ks = 0; ks < 2; ++ks)
          ac[mt][nt] = __builtin_amdgcn_mfma_f32_16x16x32_bf16(
              a[mt][ks], bb[nt][ks], ac[mt][nt], 0, 0, 0);
  };

  // Prologue: kt0 fully (4 half-tiles) + kt1 {A0,B0,B1}; A1 of kt+1 is always
  // staged in ph1 of kt. vmcnt(6) -> kt0's 8 loads done, kt1's 6 in flight.
  stageA(0, 0, 0); stageB(0, 0, 0); stageB(0, 1, 0); stageA(0, 1, 0);
  stageA(1, 0, 1); stageB(1, 0, 1); stageB(1, 1, 1);
  asm volatile("s_waitcnt vmcnt(6)" ::: "memory");
  __builtin_amdgcn_s_barrier();

  // Region-freedom schedule (stage target last read >=1 barrier earlier):
  //  ph1 reads A[b][0],B[b][0]; stages (kt+1).A1 -> As[b^1][1] (read kt-1 ph3)
  //  ph2 reads B[b][1];          stages (kt+2).A0 -> As[b][0]  (read ph1)
  //  ph3 reads A[b][1];          stages (kt+2).B0 -> Bs[b][0]  (read ph1)
  //  ph4 (regs only);            stages (kt+2).B1 -> Bs[b][1]  (read ph2)
  auto ktile = [&](int kt, int b) {
    // phase 1: quadrant (m-half0, n-half0)
    loadA(b, 0);
    loadB(b0, b, 0);
    if (kt + 1 < NK) stageA(b ^ 1, 1, kt + 1);
    PH_MID();
    mfma16(acc00, b0);
    PH_END();
    // phase 2: (m-half0, n-half1)
    loadB(b1, b, 1);
    if (kt + 2 < NK) stageA(b, 0, kt + 2);
    PH_MID();
    mfma16(acc01, b1);
    PH_END();
    // phase 3: (m-half1, n-half1)
    loadA(b, 1);
    if (kt + 2 < NK) stageB(b, 0, kt + 2);
    PH_MID();
    mfma16(acc11, b1);
    PH_END();
    // phase 4: (m-half1, n-half0) — no ds_reads; counted vmcnt once per K-tile
    if (kt + 2 < NK) {
      stageB(b, 1, kt + 2);
      asm volatile("s_waitcnt vmcnt(6)" ::: "memory");
    } else {
      asm volatile("s_waitcnt vmcnt(0)" ::: "memory");
    }
    PH_MID();
    mfma16(acc10, b0);
    PH_END();
  };
  for (int kt = 0; kt < NK; kt += 2) {
    ktile(kt, 0);
    ktile(kt + 1, 1);
  }

  // Epilogue. C/D layout: col = lane&15, row = (lane>>4)*4 + reg.
  auto writeQ = [&](f32x4 (&ac)[4][2], int mh, int nh) {
#pragma unroll
    for (int mt = 0; mt < 4; ++mt)
#pragma unroll
      for (int nt = 0; nt < 2; ++nt)
#pragma unroll
        for (int v = 0; v < 4; ++v) {
          const int row = gm0 + wm * 128 + mh * 64 + mt * 16 + q * 4 + v;
          const int col = nloc0 + wn * 64 + nh * 32 + nt * 16 + rowl;
          const size_t idx = (size_t)row * NDIM + col;
          float val = ac[mt][nt][v];
          if (zp.mode == 1) val = 2.0f * val - bf2f(zp.Cp[idx]);
          if (zp.mode == 2) val = 2.0f * val - (row == col ? 1.0f : 0.0f);
          outb[idx] = f2bf(val);
        }
  };
  writeQ(acc00, 0, 0);
  writeQ(acc01, 0, 1);
  writeQ(acc11, 1, 1);
  writeQ(acc10, 1, 0);
}

// 128x128 tile, 4 waves (2x2), 16x16x32 bf16 MFMA, global_load_lds width-16.
// Kept for S1/S2 (small grids: 288/576 blocks at 128^2 vs 72/144 at 256^2).
__global__ __launch_bounds__(256) void gemm_k(ZSet4 zs) {
  const ZSet zp = zs.z[blockIdx.z];
  __shared__ __align__(16) unsigned short As[128 * 32];
  __shared__ __align__(16) unsigned short Bs[128 * 32];
  const int tid = threadIdx.x;
  const int lane = tid & 63;
  const int wave = tid >> 6;
  const int wm = wave >> 1, wn = wave & 1;
  const int gm0 = blockIdx.y * 128;
  const int jn = blockIdx.x / 12;             // which B/out plane along N
  const int nloc0 = (blockIdx.x % 12) * 128;  // col within plane
  const int q = lane >> 4;
  const int rowl = lane & 15;

  const unsigned short* Btb = zp.Bt + (size_t)jn * PM;
  unsigned short* outb = zp.out + (size_t)jn * 5 * PM;

  f32x4 acc[4][4] = {};

  for (int k0 = 0; k0 < NDIM; k0 += 32) {
#pragma unroll
    for (int l = 0; l < 2; ++l) {
      int f = l * 256 + wave * 64 + lane;  // 512 16B chunks per 128x32 tile
      int r = f >> 2, kc = f & 3;
      const unsigned short* ga = zp.A + (size_t)(gm0 + r) * NDIM + k0 + kc * 8;
      const unsigned short* gb = Btb + (size_t)(nloc0 + r) * NDIM + k0 + kc * 8;
      unsigned short* la = &As[(size_t)(l * 256 + wave * 64) * 8];
      unsigned short* lb = &Bs[(size_t)(l * 256 + wave * 64) * 8];
      gload_lds16(ga, la);
      gload_lds16(gb, lb);
    }
    __syncthreads();
    bf16x8 af[4], bfv[4];
#pragma unroll
    for (int t = 0; t < 4; ++t) {
      af[t] = *(const bf16x8*)&As[(wm * 64 + t * 16 + rowl) * 32 + q * 8];
      bfv[t] = *(const bf16x8*)&Bs[(wn * 64 + t * 16 + rowl) * 32 + q * 8];
    }
#pragma unroll
    for (int mt = 0; mt < 4; ++mt)
#pragma unroll
      for (int nt = 0; nt < 4; ++nt)
        acc[mt][nt] = __builtin_amdgcn_mfma_f32_16x16x32_bf16(
            af[mt], bfv[nt], acc[mt][nt], 0, 0, 0);
    __syncthreads();
  }

  // C/D layout: col = lane&15, row = (lane>>4)*4 + reg
#pragma unroll
  for (int mt = 0; mt < 4; ++mt) {
#pragma unroll
    for (int nt = 0; nt < 4; ++nt) {
#pragma unroll
      for (int v = 0; v < 4; ++v) {
        int row = gm0 + wm * 64 + mt * 16 + q * 4 + v;
        int col = nloc0 + wn * 64 + nt * 16 + rowl;
        size_t idx = (size_t)row * NDIM + col;
        float val = acc[mt][nt][v];
        if (zp.mode == 1) val = 2.0f * val - bf2f(zp.Cp[idx]);
        if (zp.mode == 2) val = 2.0f * val - (row == col ? 1.0f : 0.0f);
        outb[idx] = f2bf(val);
      }
    }
  }
}

// X^T (bf16, transposed) AND straight bf16 cast of X in one pass.
__global__ void transpose_f2b(const float* __restrict__ in,
                              unsigned short* __restrict__ out16,
                              unsigned short* __restrict__ outS) {
  __shared__ float tile[32][33];
  int bx = blockIdx.x, by = blockIdx.y;
  int tx = threadIdx.x;
#pragma unroll
  for (int r = threadIdx.y; r < 32; r += 8) {
    float v = in[(size_t)(by * 32 + r) * NDIM + bx * 32 + tx];
    tile[r][tx] = v;
    outS[(size_t)(by * 32 + r) * NDIM + bx * 32 + tx] = f2bf(v);
  }
  __syncthreads();
  int ox = by * 32 + tx;
#pragma unroll
  for (int r = threadIdx.y; r < 32; r += 8)
    out16[(size_t)(bx * 32 + r) * NDIM + ox] = f2bf(tile[tx][r]);
}

// Two-plane bf16 cast (Lr and Lc in one dispatch via blockIdx.y).
__global__ void cast2_bf16_k(const float* __restrict__ inA,
                             unsigned short* __restrict__ outA,
                             const float* __restrict__ inB,
                             unsigned short* __restrict__ outB) {
  const float* in = blockIdx.y ? inB : inA;
  unsigned short* out = blockIdx.y ? outB : outA;
  int i = (blockIdx.x * 256 + threadIdx.x) * 4;
  float4 v = *(const float4*)(in + i);
  ushort4 r;
  r.x = f2bf(v.x); r.y = f2bf(v.y); r.z = f2bf(v.z); r.w = f2bf(v.w);
  *(ushort4*)(out + i) = r;
}

// Z: 25 bf16 planes, plane c = j*5+i. theta flat: i*160 + j*32 + o.
// R7: 4 px/thread, Z held PACKED in uint2 zr[25] (50 VGPR), unpacked per use.
// PLAIN bounds(256) — no min-wave clamp (the (256,4) clamp in R6 forced
// 64 VGPR < live set -> scratch spill, 435 us). theta/bias in LDS (broadcast
// ds_read). Nontemporal out stores: 302 MB streaming writes must not evict
// L3-resident Z. Accumulation order over c identical to all prior versions.
__global__ __launch_bounds__(256) void combine_k(
    const unsigned short* __restrict__ Z,
    const float* __restrict__ theta,
    const float* __restrict__ bias,
    float* __restrict__ out) {
  __shared__ float th[800];
  __shared__ float bs[32];
  const int tid = threadIdx.x;
  for (int t = tid; t < 800; t += 256) th[t] = theta[t];
  if (tid < 32) bs[tid] = bias[tid];
  __syncthreads();

  const size_t p0 = (size_t)(blockIdx.x * 256 + tid) * 4;
  uint2 zr[25];
#pragma unroll
  for (int c = 0; c < 25; ++c)
    zr[c] = *(const uint2*)(Z + (size_t)c * PM + p0);

#pragma unroll 4
  for (int o = 0; o < 32; ++o) {
    float b = bs[o];
    float a0 = b, a1 = b, a2 = b, a3 = b;
#pragma unroll
    for (int c = 0; c < 25; ++c) {
      const int i = c % 5, j = c / 5;       // compile-time after unroll
      float t = th[i * 160 + j * 32 + o];   // uniform addr -> broadcast
      a0 += t * __uint_as_float(zr[c].x << 16);
      a1 += t * __uint_as_float(zr[c].x & 0xffff0000u);
      a2 += t * __uint_as_float(zr[c].y << 16);
      a3 += t * __uint_as_float(zr[c].y & 0xffff0000u);
    }
    f32x4 w = {a0, a1, a2, a3};
    __builtin_nontemporal_store(w, (f32x4*)(out + (size_t)o * PM + p0));
  }
}

extern "C" void kernel_launch(void* const* d_in, const int* in_sizes, int n_in,
                              void* d_out, int out_size, void* d_ws, size_t ws_size,
                              hipStream_t stream) {
  (void)in_sizes; (void)n_in; (void)out_size; (void)ws_size;
  const float* X = (const float*)d_in[0];
  const float* Lr = (const float*)d_in[1];
  const float* Lc = (const float*)d_in[2];
  const float* theta = (const float*)d_in[3];
  const float* bias = (const float*)d_in[4];
  float* out = (float*)d_out;

  // Workspace: Zall(25) + Tr(4) + Tc(4) + Xt(1) = 34 bf16 planes = 160 MiB
  unsigned short* Zall = (unsigned short*)d_ws;      // plane c = j*5 + i
  unsigned short* Tr = Zall + (size_t)25 * PM;       // [Lr, T2r, T3r, T4r]
  unsigned short* Tc = Tr + (size_t)4 * PM;          // [Lc, T2c, T3c, T4c]
  unsigned short* Xt = Tc + (size_t)4 * PM;

  unsigned short* Tr0 = Tr;                 unsigned short* Tc0 = Tc;
  unsigned short* Tr1 = Tr + (size_t)PM;    unsigned short* Tc1 = Tc + (size_t)PM;
  unsigned short* Tr2 = Tr + (size_t)2*PM;  unsigned short* Tc2 = Tc + (size_t)2*PM;
  unsigned short* Tr3 = Tr + (size_t)3*PM;  unsigned short* Tc3 = Tc + (size_t)3*PM;

  cast2_bf16_k<<<dim3(PM / 1024, 2), 256, 0, stream>>>(Lr, Tr0, Lc, Tc0);
  // X: transposed bf16 (Xt) + straight bf16 (Zall plane 0) in one pass
  transpose_f2b<<<dim3(48, 48), dim3(32, 8), 0, stream>>>(X, Xt, Zall);

  // S1: T2r = 2*Lr@Lr - I ; T2c = 2*Lc@Lc - I      (z-batched, 128^2 kernel)
  {
    ZSet4 a{};
    a.z[0] = {Tr0, Tr0, Tr1, nullptr, 2};
    a.z[1] = {Tc0, Tc0, Tc1, nullptr, 2};
    gemm_k<<<dim3(12, 12, 2), 256, 0, stream>>>(a);
  }
  // S2: T3 = 2*L@T2 - L ; T4 = 2*T2@T2 - I   (both axes, z-batched)
  {
    ZSet4 a{};
    a.z[0] = {Tr0, Tr1, Tr2, Tr0, 1};
    a.z[1] = {Tr1, Tr1, Tr3, nullptr, 2};
    a.z[2] = {Tc0, Tc1, Tc2, Tc0, 1};
    a.z[3] = {Tc1, Tc1, Tc3, nullptr, 2};
    gemm_k<<<dim3(12, 12, 4), 256, 0, stream>>>(a);
  }
  // G1: Y_j = T_j(Lr) @ X, j=1..4  -> Zall planes 1..4.  A = Tr stacked
  // (M=6144), B^T = Xt, N=1536 (jn==0). 256^2 8-phase kernel.
  {
    ZSet4 a{};
    a.z[0] = {Tr, Xt, Zall + (size_t)PM, nullptr, 0};
    gemm256_k<<<dim3(6, 24, 1), 512, 0, stream>>>(a);
  }
  // G2: Z_{i,j} = Y_i @ T_j(Lc). A = Zall[0..4] (M=7680), B planes via jn,
  // out plane group stride 5*PM -> Zall plane (1+jn)*5 + i. 256^2 kernel.
  {
    ZSet4 a{};
    a.z[0] = {Zall, Tc0, Zall + (size_t)5 * PM, nullptr, 0};
    gemm256_k<<<dim3(24, 30, 1), 512, 0, stream>>>(a);
  }

  combine_k<<<PM / 1024, 256, 0, stream>>>(Zall, theta, bias, out);
}